// Round 1
// baseline (598.769 us; speedup 1.0000x reference)
//
#include <hip/hip_runtime.h>
#include <stdint.h>

#define GAS __attribute__((address_space(1)))
#define LAS __attribute__((address_space(3)))

typedef __attribute__((ext_vector_type(8))) short short8;
typedef __attribute__((ext_vector_type(4))) float float4v;
typedef __attribute__((ext_vector_type(4))) unsigned int uint4v;

__device__ __forceinline__ unsigned short f2bf(float f) {
  union { float f; unsigned int u; } v; v.f = f;
  unsigned int r = v.u + 0x7fffu + ((v.u >> 16) & 1u);
  return (unsigned short)(r >> 16);
}

__device__ __forceinline__ void async_g2l16(const void* g, void* l) {
  __builtin_amdgcn_global_load_lds((const GAS unsigned int*)g,
                                   (LAS unsigned int*)l, 16, 0, 0);
}

// ---------------- Kernel A: normalize y -> bf16 [dy][dx][o][c] swizzled ----
__global__ void knorm_y(const float* __restrict__ y, unsigned short* __restrict__ y_t) {
  int o = blockIdx.x;
  int tid = threadIdx.x;
  const float* yo = y + o * 16384;
  float s = 0.f;
  for (int idx = tid; idx < 16384; idx += 256) { float v = yo[idx]; s += v * v; }
  for (int off = 32; off; off >>= 1) s += __shfl_down(s, off, 64);
  __shared__ float red[4];
  if ((tid & 63) == 0) red[tid >> 6] = s;
  __syncthreads();
  float rn = 1.0f / sqrtf(red[0] + red[1] + red[2] + red[3]);
  for (int idx = tid; idx < 16384; idx += 256) {
    int c = idx >> 8, dy = (idx >> 4) & 15, dx = idx & 15;
    unsigned short b = f2bf(yo[idx] * rn);
    int dst = ((dy * 16 + dx) * 64 + o) * 64 + (((c >> 3) ^ (o & 7)) << 3) + (c & 7);
    y_t[dst] = b;
  }
}

// ------- Kernel B: x (NCHW f32) -> x_t bf16 [n][h][col][c] swizzled, + s ---
__global__ void ktrans_x(const float* __restrict__ x, unsigned short* __restrict__ x_t,
                         float* __restrict__ s) {
  int h = blockIdx.x, n = blockIdx.y;
  int tid = threadIdx.x;
  __shared__ __align__(16) unsigned short tb[8192];
  __shared__ float sb[256];
  const float* xb = x + ((size_t)n * 64) * 16384 + h * 128;  // (n, c=0, h, w=0)
  for (int idx = tid; idx < 8192; idx += 256) {
    int c = idx >> 7, w = idx & 127;
    float v = xb[(size_t)c * 16384 + w];
    tb[w * 64 + (((c >> 3) ^ (w & 7)) << 3) + (c & 7)] = f2bf(v);
  }
  int w = tid & 127, half = tid >> 7;
  float acc = 0.f;
  for (int c = half * 32; c < half * 32 + 32; ++c) {
    float v = xb[(size_t)c * 16384 + w];
    acc += v * v;
  }
  sb[tid] = acc;
  __syncthreads();
  uint4v* dst = (uint4v*)(x_t + ((size_t)(n * 128 + h)) * 8192);
  const uint4v* src = (const uint4v*)tb;
  for (int idx = tid; idx < 1024; idx += 256) dst[idx] = src[idx];
  if (tid < 128) s[((size_t)(n * 128 + h)) * 128 + tid] = sb[tid] + sb[tid + 128];
}

// ---------------- Kernel D: 16x16 box sum of s -> 1/sqrt ------------------
__global__ void knorm_x(const float* __restrict__ s, float* __restrict__ invn) {
  int idx = blockIdx.x * 256 + threadIdx.x;
  if (idx >= 16 * 113 * 113) return;
  int n = idx / 12769, r = idx % 12769;
  int i = r / 113, j = r % 113;
  const float* sp = s + ((size_t)n * 128 + i) * 128 + j;
  float acc = 0.f;
#pragma unroll
  for (int dy = 0; dy < 16; ++dy) {
    float rowacc = 0.f;
#pragma unroll
    for (int dx = 0; dx < 16; ++dx) rowacc += sp[dy * 128 + dx];
    acc += rowacc;
  }
  invn[idx] = 1.0f / sqrtf(acc);
}

// ---------------- Kernel E: main implicit-GEMM conv -----------------------
// block = (row i, image n). Tile M=128 (cols j, padded from 113), N=64 (o).
// K-loop: 256 (dy,dx) iters x (c=64 as 2 cbase of 32).
__launch_bounds__(256, 2)
__global__ void kconv(const unsigned short* __restrict__ x_t,
                      const unsigned short* __restrict__ y_t,
                      const float* __restrict__ invn,
                      float* __restrict__ out) {
  int i = blockIdx.x;
  int n = blockIdx.y;
  int tid = threadIdx.x;
  int lane = tid & 63, wave = tid >> 6;
  int lane15 = lane & 15, q = lane >> 4;
  int wrow = wave >> 1, wcol = wave & 1;

  __shared__ __align__(16) char smem[49152];
  char* const A0 = smem;
  char* const A1 = smem + 16384;
  char* const B0 = smem + 32768;
  char* const B1 = smem + 40960;

  const char* xrow0 = (const char*)(x_t + ((size_t)(n * 128 + i)) * 8192);

  auto stageA = [&](int dy, char* buf) {
    const char* src = xrow0 + (size_t)dy * 16384;
#pragma unroll
    for (int it = 0; it < 4; ++it) {
      int chunk = it * 256 + wave * 64;  // wave-uniform
      async_g2l16(src + (chunk + lane) * 16, buf + chunk * 16);
    }
  };
  auto stageB = [&](int t, char* buf) {
    const char* src = (const char*)(y_t + (size_t)t * 4096);
#pragma unroll
    for (int it = 0; it < 2; ++it) {
      int chunk = it * 256 + wave * 64;  // wave-uniform
      async_g2l16(src + (chunk + lane) * 16, buf + chunk * 16);
    }
  };

  float4v acc[4][2];
#pragma unroll
  for (int mt = 0; mt < 4; ++mt)
#pragma unroll
    for (int nt = 0; nt < 2; ++nt) acc[mt][nt] = (float4v){0.f, 0.f, 0.f, 0.f};

  // B-fragment LDS byte offsets (fixed across the whole K-loop)
  int boff[2][2];
#pragma unroll
  for (int nt = 0; nt < 2; ++nt)
#pragma unroll
    for (int cb = 0; cb < 2; ++cb) {
      int o = wcol * 32 + nt * 16 + lane15;
      boff[nt][cb] = o * 128 + (((q + cb * 4) ^ (o & 7)) << 4);
    }
  // A-fragment per-mt base (col*128), col = wrow*64 + mt*16 + lane15 (+dx later)
  int abase[4];
#pragma unroll
  for (int mt = 0; mt < 4; ++mt) abase[mt] = (wrow * 64 + mt * 16 + lane15) * 128;

  stageB(0, B0);
  stageA(0, A0);
  __syncthreads();

#pragma unroll 1
  for (int t = 0; t < 256; ++t) {
    int dx = t & 15, dy = t >> 4;
    if (t < 255) {
      stageB(t + 1, (t & 1) ? B0 : B1);
      if (((t + 1) & 15) == 0) stageA((t + 1) >> 4, ((((t + 1) >> 4) & 1) ? A1 : A0));
    }
    char* Ab = (dy & 1) ? A1 : A0;
    char* Bb = (t & 1) ? B1 : B0;

    short8 bf[2][2];
#pragma unroll
    for (int nt = 0; nt < 2; ++nt)
#pragma unroll
      for (int cb = 0; cb < 2; ++cb) bf[nt][cb] = *(const short8*)(Bb + boff[nt][cb]);

    int xr = (lane15 + dx) & 7;
#pragma unroll
    for (int cb = 0; cb < 2; ++cb) {
      int aoff = dx * 128 + ((((q + cb * 4) ^ xr)) << 4);
#pragma unroll
      for (int mt = 0; mt < 4; ++mt) {
        short8 a = *(const short8*)(Ab + abase[mt] + aoff);
        acc[mt][0] = __builtin_amdgcn_mfma_f32_16x16x32_bf16(a, bf[0][cb], acc[mt][0], 0, 0, 0);
        acc[mt][1] = __builtin_amdgcn_mfma_f32_16x16x32_bf16(a, bf[1][cb], acc[mt][1], 0, 0, 0);
      }
    }
    __syncthreads();
  }

  // Epilogue: transpose through LDS to [o][j], fuse /x_norm + relu, coalesced store
  float* cs = (float*)smem;  // 64 x 132 floats (padded) = 33792 B
#pragma unroll
  for (int mt = 0; mt < 4; ++mt)
#pragma unroll
    for (int nt = 0; nt < 2; ++nt) {
      int o = wcol * 32 + nt * 16 + lane15;
      int j0 = wrow * 64 + mt * 16 + q * 4;
      *(float4v*)(cs + o * 132 + j0) = acc[mt][nt];
    }
  __syncthreads();
  const float* ivp = invn + ((size_t)n * 113 + i) * 113;
  float* op = out + (size_t)n * 64 * 12769 + (size_t)i * 113;
  for (int idx = tid; idx < 8192; idx += 256) {
    int o = idx >> 7, j = idx & 127;
    if (j < 113) {
      float v = cs[o * 132 + j] * ivp[j];
      op[(size_t)o * 12769 + j] = fmaxf(v, 0.f);
    }
  }
}

extern "C" void kernel_launch(void* const* d_in, const int* in_sizes, int n_in,
                              void* d_out, int out_size, void* d_ws, size_t ws_size,
                              hipStream_t stream) {
  const float* x = (const float*)d_in[0];
  const float* y = (const float*)d_in[1];
  float* out = (float*)d_out;
  char* ws = (char*)d_ws;
  unsigned short* x_t = (unsigned short*)ws;                 // 33,554,432 B
  unsigned short* y_t = (unsigned short*)(ws + 33554432);    //  2,097,152 B
  float* s = (float*)(ws + 35651584);                        //  1,048,576 B
  float* invn = (float*)(ws + 36700160);                     //    817,216 B

  hipLaunchKernelGGL(knorm_y, dim3(64), dim3(256), 0, stream, y, y_t);
  hipLaunchKernelGGL(ktrans_x, dim3(128, 16), dim3(256), 0, stream, x, x_t, s);
  hipLaunchKernelGGL(knorm_x, dim3(799), dim3(256), 0, stream, s, invn);
  hipLaunchKernelGGL(kconv, dim3(113, 16), dim3(256), 0, stream, x_t, y_t, invn, out);
}

// Round 3
// 546.490 us; speedup vs baseline: 1.0957x; 1.0957x over previous
//
#include <hip/hip_runtime.h>
#include <stdint.h>

#define GAS __attribute__((address_space(1)))
#define LAS __attribute__((address_space(3)))

typedef __attribute__((ext_vector_type(8))) short short8;
typedef __attribute__((ext_vector_type(4))) float float4v;
typedef __attribute__((ext_vector_type(4))) unsigned int uint4v;

__device__ __forceinline__ unsigned short f2bf(float f) {
  union { float f; unsigned int u; } v; v.f = f;
  unsigned int r = v.u + 0x7fffu + ((v.u >> 16) & 1u);
  return (unsigned short)(r >> 16);
}

__device__ __forceinline__ void async_g2l16(const void* g, void* l) {
  __builtin_amdgcn_global_load_lds((const GAS unsigned int*)g,
                                   (LAS unsigned int*)l, 16, 0, 0);
}

// Full VMEM drain: guarantees all in-flight global_load_lds (LDS-DMA) have
// landed in LDS before the following s_barrier, independent of the
// compiler's LDS-DMA waitcnt tracking.
__device__ __forceinline__ void vmem_drain() {
  asm volatile("s_waitcnt vmcnt(0)" ::: "memory");
}

// ---- Kernel A: normalize y -> bf16 fragment-major [t][og][cb][lane][8] ----
// For t=dy*16+dx: fragment (og,cb) is 1KB; lane = q*16 + (o&15), holds
// o = og*16+(o&15), c = cb*32 + q*8 + j  (exactly the 16x16x32 B-operand map).
__global__ void knorm_y(const float* __restrict__ y, unsigned short* __restrict__ y_t2) {
  int o = blockIdx.x;
  int tid = threadIdx.x;
  const float* yo = y + o * 16384;
  float s = 0.f;
  for (int idx = tid; idx < 16384; idx += 256) { float v = yo[idx]; s += v * v; }
  for (int off = 32; off; off >>= 1) s += __shfl_down(s, off, 64);
  __shared__ float red[4];
  if ((tid & 63) == 0) red[tid >> 6] = s;
  __syncthreads();
  float rn = 1.0f / sqrtf(red[0] + red[1] + red[2] + red[3]);
  int og = o >> 4, ol = o & 15;
  for (int idx = tid; idx < 16384; idx += 256) {
    int c = idx >> 8, dy = (idx >> 4) & 15, dx = idx & 15;
    int t = dy * 16 + dx;
    int cb = c >> 5, q = (c >> 3) & 3, j = c & 7;
    size_t dst = (size_t)t * 4096 + (size_t)(og * 2 + cb) * 512 + (q * 16 + ol) * 8 + j;
    y_t2[dst] = f2bf(yo[idx] * rn);
  }
}

// ------- Kernel B: x (NCHW f32) -> x_t bf16 [n][h][w][c] swizzled, + s -----
__global__ void ktrans_x(const float* __restrict__ x, unsigned short* __restrict__ x_t,
                         float* __restrict__ s) {
  int h = blockIdx.x, n = blockIdx.y;
  int tid = threadIdx.x;
  __shared__ __align__(16) unsigned short tb[8192];
  __shared__ float sb[256];
  const float* xb = x + ((size_t)n * 64) * 16384 + h * 128;
  int w = tid & 127, half = tid >> 7;
  float acc = 0.f;
#pragma unroll
  for (int cs = 0; cs < 4; ++cs) {
    short8 tmp;
#pragma unroll
    for (int j = 0; j < 8; ++j) {
      int c = half * 32 + cs * 8 + j;
      float v = xb[(size_t)c * 16384 + w];
      tmp[j] = (short)f2bf(v);
      acc += v * v;
    }
    int chunk = (half * 4 + cs) ^ (w & 7);
    *(short8*)(tb + w * 64 + chunk * 8) = tmp;
  }
  sb[tid] = acc;
  __syncthreads();
  uint4v* dst = (uint4v*)(x_t + ((size_t)(n * 128 + h)) * 8192);
  const uint4v* src = (const uint4v*)tb;
  for (int idx = tid; idx < 1024; idx += 256) dst[idx] = src[idx];
  if (tid < 128) s[((size_t)(n * 128 + h)) * 128 + tid] = sb[tid] + sb[tid + 128];
}

// ---------------- Kernel D: separable 16x16 box sum of s -> 1/sqrt --------
__global__ void knorm_x(const float* __restrict__ s, float* __restrict__ invn) {
  int i = blockIdx.x, n = blockIdx.y;
  int tid = threadIdx.x;  // 128
  __shared__ float colsum[128];
  const float* sp = s + ((size_t)(n * 128 + i)) * 128;
  float a = 0.f;
#pragma unroll
  for (int dy = 0; dy < 16; ++dy) a += sp[dy * 128 + tid];
  colsum[tid] = a;
  __syncthreads();
  if (tid < 113) {
    float acc = 0.f;
#pragma unroll
    for (int dx = 0; dx < 16; ++dx) acc += colsum[tid + dx];
    invn[((size_t)n * 113 + i) * 113 + tid] = 1.0f / sqrtf(acc);
  }
}

// ---------------- Kernel E: main implicit-GEMM conv -----------------------
// block = (row i, image n). Tile M=128 (cols j), N=64 (o).
// A (x row) staged in LDS per dy (double-buffered, barrier 1x per 16 iters,
// explicit vmcnt(0) drain before each barrier for LDS-DMA correctness).
// B fragments loaded global->VGPR (L2-resident), pipelined one t ahead.
__launch_bounds__(256, 3)
__global__ void kconv(const unsigned short* __restrict__ x_t,
                      const unsigned short* __restrict__ y_t2,
                      const float* __restrict__ invn,
                      float* __restrict__ out) {
  int i = blockIdx.x;
  int n = blockIdx.y;
  int tid = threadIdx.x;
  int lane = tid & 63, wave = tid >> 6;
  int lane15 = lane & 15, q = lane >> 4;
  int wrow = wave >> 1, wcol = wave & 1;

  __shared__ __align__(16) char smem[32768];
  char* const A0 = smem;
  char* const A1 = smem + 16384;

  const char* xrow0 = (const char*)(x_t + ((size_t)(n * 128 + i)) * 8192);

  auto stageA = [&](int dy, char* buf) {
    const char* src = xrow0 + (size_t)dy * 16384;
#pragma unroll
    for (int it = 0; it < 4; ++it) {
      int chunk = it * 256 + wave * 64;  // wave-uniform LDS base
      async_g2l16(src + (chunk + lane) * 16, buf + chunk * 16);
    }
  };

  const short8* ybase = (const short8*)(y_t2 + (size_t)wcol * 2048 + (size_t)lane * 8);
  auto loadB = [&](int t, short8 bf[2][2]) {
    const short8* p = ybase + (size_t)t * 512;  // 512 short8 = 4096 shorts per t
    bf[0][0] = p[0];
    bf[0][1] = p[64];
    bf[1][0] = p[128];
    bf[1][1] = p[192];
  };

  float4v acc[4][2];
#pragma unroll
  for (int mt = 0; mt < 4; ++mt)
#pragma unroll
    for (int nt = 0; nt < 2; ++nt) acc[mt][nt] = (float4v){0.f, 0.f, 0.f, 0.f};

  int abase[4];
#pragma unroll
  for (int mt = 0; mt < 4; ++mt) abase[mt] = (wrow * 64 + mt * 16 + lane15) * 128;

  stageA(0, A0);
  short8 bc[2][2];
  loadB(0, bc);
  vmem_drain();
  __syncthreads();

#pragma unroll 1
  for (int dy = 0; dy < 16; ++dy) {
    char* Ab = (dy & 1) ? A1 : A0;
    if (dy < 15) stageA(dy + 1, (dy & 1) ? A0 : A1);
#pragma unroll
    for (int dx = 0; dx < 16; ++dx) {
      int t = dy * 16 + dx;
      short8 bn[2][2];
      if (t < 255) loadB(t + 1, bn);
      int xr = (lane15 + dx) & 7;
#pragma unroll
      for (int cb = 0; cb < 2; ++cb) {
        int aoff = dx * 128 + (((q + cb * 4) ^ xr) << 4);
#pragma unroll
        for (int mt = 0; mt < 4; ++mt) {
          short8 a = *(const short8*)(Ab + abase[mt] + aoff);
          acc[mt][0] = __builtin_amdgcn_mfma_f32_16x16x32_bf16(a, bc[0][cb], acc[mt][0], 0, 0, 0);
          acc[mt][1] = __builtin_amdgcn_mfma_f32_16x16x32_bf16(a, bc[1][cb], acc[mt][1], 0, 0, 0);
        }
      }
      if (t < 255) {
        bc[0][0] = bn[0][0]; bc[0][1] = bn[0][1];
        bc[1][0] = bn[1][0]; bc[1][1] = bn[1][1];
      }
    }
    // Drain LDS-DMA (stageA(dy+1)) before the buffer-swap barrier. Without
    // this, ds_reads of the next dy can race in-flight DMA writes (R1 bug).
    vmem_drain();
    __syncthreads();
  }

  // Epilogue: two-pass transpose through LDS (o-halves), fuse invn + relu.
  float* cs = (float*)smem;        // 32 x 132 floats = 16896 B
  float* ivs = cs + 4352;          // 128 floats
  const float* ivp = invn + ((size_t)n * 113 + i) * 113;
  if (tid < 128) ivs[tid] = (tid < 113) ? ivp[tid] : 0.f;
  float* op = out + (size_t)n * 64 * 12769 + (size_t)i * 113;
#pragma unroll 1
  for (int p = 0; p < 2; ++p) {
    if (wcol == p) {
#pragma unroll
      for (int mt = 0; mt < 4; ++mt)
#pragma unroll
        for (int nt = 0; nt < 2; ++nt) {
          int row = nt * 16 + lane15;
          int j0 = wrow * 64 + mt * 16 + q * 4;
          *(float4v*)(cs + row * 132 + j0) = acc[mt][nt];
        }
    }
    __syncthreads();
    for (int idx = tid; idx < 4096; idx += 256) {
      int o2 = idx >> 7, j = idx & 127;
      if (j < 113) {
        float v = cs[o2 * 132 + j] * ivs[j];
        op[(size_t)(p * 32 + o2) * 12769 + j] = fmaxf(v, 0.f);
      }
    }
    __syncthreads();
  }
}

extern "C" void kernel_launch(void* const* d_in, const int* in_sizes, int n_in,
                              void* d_out, int out_size, void* d_ws, size_t ws_size,
                              hipStream_t stream) {
  const float* x = (const float*)d_in[0];
  const float* y = (const float*)d_in[1];
  float* out = (float*)d_out;
  char* ws = (char*)d_ws;
  unsigned short* x_t = (unsigned short*)ws;                 // 33,554,432 B
  unsigned short* y_t2 = (unsigned short*)(ws + 33554432);   //  2,097,152 B
  float* s = (float*)(ws + 35651584);                        //  1,048,576 B
  float* invn = (float*)(ws + 36700160);                     //    817,216 B

  hipLaunchKernelGGL(knorm_y, dim3(64), dim3(256), 0, stream, y, y_t2);
  hipLaunchKernelGGL(ktrans_x, dim3(128, 16), dim3(256), 0, stream, x, x_t, s);
  hipLaunchKernelGGL(knorm_x, dim3(113, 16), dim3(128), 0, stream, s, invn);
  hipLaunchKernelGGL(kconv, dim3(113, 16), dim3(256), 0, stream, x_t, y_t2, invn, out);
}